// Round 2
// baseline (72.147 us; speedup 1.0000x reference)
//
#include <hip/hip_runtime.h>
#include <hip/hip_bf16.h>

typedef __bf16 bf16;
typedef __bf16 bf16x2 __attribute__((ext_vector_type(2)));
typedef __bf16 bf16x4 __attribute__((ext_vector_type(4)));
typedef __bf16 bf16x8 __attribute__((ext_vector_type(8)));
typedef float f32x4 __attribute__((ext_vector_type(4)));

#define NB 8
#define L_ 4096
#define C_ 512
#define KW 5
#define NS 8
#define BM 64
#define BN 256
#define BK 32
#define KSTEPS (C_ / BK) /* 16 */

// ---------------------------------------------------------------------------
// prep: w_pw fp32 -> bf16; bias2[n] = b_pw[n] + sum_k b_dw[k]*w_pw[n][k]
// ---------------------------------------------------------------------------
__global__ __launch_bounds__(256) void prep_kernel(
    const float* __restrict__ w_pw, const float* __restrict__ b_dw,
    const float* __restrict__ b_pw, bf16* __restrict__ wbf,
    float* __restrict__ bias2) {
  const int n = blockIdx.x;   // 0..511
  const int t = threadIdx.x;  // 0..255
  float2 v = *(const float2*)(w_pw + n * C_ + 2 * t);
  bf16x2 hv;
  hv[0] = (bf16)v.x;
  hv[1] = (bf16)v.y;
  *(bf16x2*)(wbf + n * C_ + 2 * t) = hv;
  float2 bb = *(const float2*)(b_dw + 2 * t);
  float s = v.x * bb.x + v.y * bb.y;
#pragma unroll
  for (int off = 32; off; off >>= 1) s += __shfl_down(s, off, 64);
  __shared__ float part[4];
  if ((t & 63) == 0) part[t >> 6] = s;
  __syncthreads();
  if (t == 0) bias2[n] = b_pw[n] + part[0] + part[1] + part[2] + part[3];
}

// ---------------------------------------------------------------------------
// fused: on-the-fly segment-causal depthwise conv -> LDS (bf16, dbuf)
//        + MFMA GEMM, B streamed L2->reg with 1-step prefetch (no B LDS).
// Grid: 1024 blocks (512 M-tiles x 2 N-tiles), 256 threads (4 waves, 1Mx4N).
// ---------------------------------------------------------------------------
__global__ __launch_bounds__(256, 3) void fused_dwconv_gemm(
    const float* __restrict__ x, const int* __restrict__ segb,
    const float* __restrict__ w_dw, const float* __restrict__ b_dw,
    const bf16* __restrict__ wbf, const float* __restrict__ bias2,
    float* __restrict__ out) {
  __shared__ __align__(16) bf16 dws[2][BM][40];  // 80B rows -> 2-way max on b128
  __shared__ int segst[BM];

  const int t = threadIdx.x;
  const int lane = t & 63;
  const int wn = t >> 6;  // 0..3 (each wave = 1 wave/SIMD)

  // XCD swizzle: keep both N-halves of an M-tile on the same XCD (x L2 reuse)
  const int bid = blockIdx.x;           // 1024 blocks, 1024%8==0
  const int swz = (bid & 7) * 128 + (bid >> 3);
  const int mtile = swz >> 1;           // 0..511
  const int nt = swz & 1;               // 0..1
  const int b = mtile >> 6;             // 4096/64 = 64 m-tiles per batch row
  const int l0 = (mtile & 63) << 6;
  const int n0 = nt << 8;

  // per-row segment start (segments partition [0,L))
  if (t < BM) {
    int l = l0 + t;
    const int* sb = segb + b * NS * 2;
    int st = 0;
#pragma unroll
    for (int s = 0; s < NS; ++s) {
      int a0 = sb[2 * s], a1 = sb[2 * s + 1];
      if (l >= a0 && l < a1) st = a0;
    }
    segst[t] = st;
  }
  __syncthreads();

  // A staging geometry: thread owns 2 rows x 4 channels per K-step
  const int c4 = t & 7;   // channel quad within BK
  const int rb = t >> 3;  // 0..31
  const int r0 = rb * 2;
  int nv0 = (l0 + r0) - segst[r0];
  if (nv0 > 4) nv0 = 4;
  int nv1 = (l0 + r0 + 1) - segst[r0 + 1];
  if (nv1 > 4) nv1 = 4;

  const float* xbase = x + (size_t)(b * L_ + l0 + r0 - 4) * C_ + c4 * 4;

  // B fragment base: row n0+wn*64+(lane&15), k-chunk (lane>>4)*8
  const bf16* wbfp =
      wbf + (size_t)(n0 + wn * 64 + (lane & 15)) * C_ + (lane >> 4) * 8;

  f32x4 acc[4][4];
#pragma unroll
  for (int i = 0; i < 4; ++i)
#pragma unroll
    for (int j = 0; j < 4; ++j) acc[i][j] = (f32x4){0.f, 0.f, 0.f, 0.f};

  auto loadB = [&](int kk, bf16x8 (&dst)[4]) {
#pragma unroll
    for (int nf = 0; nf < 4; ++nf)
      dst[nf] = *(const bf16x8*)(wbfp + nf * 16 * C_ + kk * BK);
  };

  auto stage = [&](int kk, int p) {
    const int k0 = kk * BK;
    // x rows r0-4 .. r0+1 (float4, 8-lane-contiguous), zero left edge
    float4 v[6];
#pragma unroll
    for (int m = 0; m < 6; ++m) {
      long l = (long)l0 + r0 - 4 + m;
      if (l >= 0)
        v[m] = *(const float4*)(xbase + (size_t)m * C_ + k0);
      else
        v[m] = make_float4(0.f, 0.f, 0.f, 0.f);
    }
    // w_dw rows c0..c0+3 (20 contiguous floats, 16B-aligned) + b_dw quad
    const int c0 = k0 + c4 * 4;
    float wf[20];
#pragma unroll
    for (int i = 0; i < 5; ++i)
      *(float4*)(wf + 4 * i) = *(const float4*)(w_dw + c0 * KW + 4 * i);
    const float4 bd = *(const float4*)(b_dw + c0);

#pragma unroll
    for (int j = 0; j < 2; ++j) {
      const int nv = j ? nv1 : nv0;
      bf16x4 h;
#pragma unroll
      for (int i = 0; i < 4; ++i) {
        float a = (i == 0) ? bd.x : (i == 1) ? bd.y : (i == 2) ? bd.z : bd.w;
#pragma unroll
        for (int d = 0; d <= 4; ++d) {
          float wv = (d <= nv) ? wf[i * 5 + 4 - d] : 0.f;
          float xv = ((const float*)&v[j + 4 - d])[i];
          a = fmaf(wv, xv, a);
        }
        h[i] = (bf16)a;
      }
      *(bf16x4*)&dws[p][r0 + j][c4 * 4] = h;
    }
  };

  auto mma = [&](int p, bf16x8 (&bfr)[4]) {
    bf16x8 afr[4];
#pragma unroll
    for (int mf = 0; mf < 4; ++mf)
      afr[mf] = *(const bf16x8*)&dws[p][mf * 16 + (lane & 15)][(lane >> 4) * 8];
#pragma unroll
    for (int nf = 0; nf < 4; ++nf)
#pragma unroll
      for (int mf = 0; mf < 4; ++mf)
        acc[mf][nf] = __builtin_amdgcn_mfma_f32_16x16x32_bf16(
            afr[mf], bfr[nf], acc[mf][nf], 0, 0, 0);
  };

  bf16x8 bA[4], bB[4];
  loadB(0, bA);
  stage(0, 0);
#pragma unroll 1
  for (int k2 = 0; k2 < KSTEPS; k2 += 2) {
    // even step: use bA / dws[0]; prefetch bB, stage dws[1]
    loadB(k2 + 1, bB);
    __syncthreads();
    stage(k2 + 1, 1);
    mma(0, bA);
    // odd step: use bB / dws[1]; prefetch bA, stage dws[0]
    if (k2 + 2 < KSTEPS) loadB(k2 + 2, bA);
    __syncthreads();
    if (k2 + 2 < KSTEPS) stage(k2 + 2, 0);
    mma(1, bB);
  }

  // epilogue: fp32 + bias2 (b_pw + w_pw.b_dw folded, fp32 exact)
  const int col0 = n0 + wn * 64 + (lane & 15);
  float bia[4];
#pragma unroll
  for (int nf = 0; nf < 4; ++nf) bia[nf] = bias2[col0 + nf * 16];
  const int rb0 = l0 + ((lane >> 4) << 2);
#pragma unroll
  for (int mf = 0; mf < 4; ++mf) {
#pragma unroll
    for (int i = 0; i < 4; ++i) {
      int row = rb0 + mf * 16 + i;
      float* o = out + (size_t)(b * L_ + row) * C_ + col0;
#pragma unroll
      for (int nf = 0; nf < 4; ++nf) o[nf * 16] = acc[mf][nf][i] + bia[nf];
    }
  }
}

extern "C" void kernel_launch(void* const* d_in, const int* in_sizes, int n_in,
                              void* d_out, int out_size, void* d_ws,
                              size_t ws_size, hipStream_t stream) {
  const float* x = (const float*)d_in[0];
  const int* segb = (const int*)d_in[1];      // [B][S][2] int32
  const float* w_dw = (const float*)d_in[2];  // [C][K]
  const float* b_dw = (const float*)d_in[3];  // [C]
  const float* w_pw = (const float*)d_in[4];  // [C_out][C_in]
  const float* b_pw = (const float*)d_in[5];  // [C]
  float* out = (float*)d_out;

  bf16* wbf = (bf16*)d_ws;                             // 512 KB
  float* bias2 = (float*)((char*)d_ws + C_ * C_ * 2);  // 2 KB

  prep_kernel<<<C_, 256, 0, stream>>>(w_pw, b_dw, b_pw, wbf, bias2);
  fused_dwconv_gemm<<<(NB * L_ / BM) * (C_ / BN), 256, 0, stream>>>(
      x, segb, w_dw, b_dw, wbf, bias2, out);
}

// Round 3
// 57.883 us; speedup vs baseline: 1.2464x; 1.2464x over previous
//
#include <hip/hip_runtime.h>
#include <hip/hip_bf16.h>

typedef __bf16 bf16;
typedef __bf16 bf16x2 __attribute__((ext_vector_type(2)));
typedef __bf16 bf16x4 __attribute__((ext_vector_type(4)));
typedef __bf16 bf16x8 __attribute__((ext_vector_type(8)));
typedef float f32x4 __attribute__((ext_vector_type(4)));

#define NB 8
#define L_ 4096
#define C_ 512
#define KW 5
#define NS 8
#define BM 128
#define BN 256
#define BK 32
#define KSTEPS 16

#define GLOAD_LDS16(g, l)                                                      \
  __builtin_amdgcn_global_load_lds(                                            \
      (const __attribute__((address_space(1))) void*)(g),                      \
      (__attribute__((address_space(3))) void*)(l), 16, 0, 0)

// raw barrier with counted vmem wait: keeps 6 x-loads in flight across it
#define PRE_BARRIER6                                                           \
  do {                                                                         \
    asm volatile("s_waitcnt vmcnt(6) lgkmcnt(0)" ::: "memory");                \
    __builtin_amdgcn_sched_barrier(0);                                         \
    __builtin_amdgcn_s_barrier();                                              \
    __builtin_amdgcn_sched_barrier(0);                                         \
  } while (0)
#define PRE_BARRIER0                                                           \
  do {                                                                         \
    asm volatile("s_waitcnt vmcnt(0) lgkmcnt(0)" ::: "memory");                \
    __builtin_amdgcn_sched_barrier(0);                                         \
    __builtin_amdgcn_s_barrier();                                              \
    __builtin_amdgcn_sched_barrier(0);                                         \
  } while (0)

// ---------------------------------------------------------------------------
// prep: w_pw fp32 -> bf16; bias2[n] = b_pw[n] + sum_k b_dw[k]*w_pw[n][k]
// ---------------------------------------------------------------------------
__global__ __launch_bounds__(256) void prep_kernel(
    const float* __restrict__ w_pw, const float* __restrict__ b_dw,
    const float* __restrict__ b_pw, bf16* __restrict__ wbf,
    float* __restrict__ bias2) {
  const int n = blockIdx.x;   // 0..511
  const int t = threadIdx.x;  // 0..255
  float2 v = *(const float2*)(w_pw + n * C_ + 2 * t);
  bf16x2 hv;
  hv[0] = (bf16)v.x;
  hv[1] = (bf16)v.y;
  *(bf16x2*)(wbf + n * C_ + 2 * t) = hv;
  float2 bb = *(const float2*)(b_dw + 2 * t);
  float s = v.x * bb.x + v.y * bb.y;
#pragma unroll
  for (int off = 32; off; off >>= 1) s += __shfl_down(s, off, 64);
  __shared__ float part[4];
  if ((t & 63) == 0) part[t >> 6] = s;
  __syncthreads();
  if (t == 0) bias2[n] = b_pw[n] + part[0] + part[1] + part[2] + part[3];
}

// ---------------------------------------------------------------------------
// fused: segment-causal depthwise conv (on-the-fly, bf16, LDS dbuf)
//        + MFMA GEMM. Software pipeline with raw barriers + counted vmcnt:
//        x-loads (to regs) stay in flight across barriers; B via
//        global_load_lds issued first each iter (FIFO-safe vmcnt(6)).
// Grid: 512 blocks (256 M-tiles x 2 N-tiles), 512 threads (8 waves, 2Mx4N).
// ---------------------------------------------------------------------------
__global__ __launch_bounds__(512, 2) void fused_dwconv_gemm(
    const float* __restrict__ x, const int* __restrict__ segb,
    const float* __restrict__ w_dw, const bf16* __restrict__ wbf,
    const float* __restrict__ bias2, float* __restrict__ out) {
  __shared__ __align__(16) bf16 Bs[2][BN * BK];   // 32 KB, chunk-XOR swizzled
  __shared__ __align__(16) bf16 dws[2][BM][40];   // 20 KB, 80B rows
  __shared__ __align__(16) float wdt[KW][C_];     // 10 KB, w_dw transposed
  __shared__ int segst[BM];

  const int t = threadIdx.x;
  const int lane = t & 63;
  const int wid = t >> 6;
  const int wm = wid >> 2;  // 0..1
  const int wn = wid & 3;   // 0..3

  // XCD-aware swizzle (512 % 8 == 0): both N-halves of an M-tile same XCD
  const int bid = blockIdx.x;
  const int tile = (bid & 7) * 64 + (bid >> 3);
  const int mtile = tile >> 1;      // 0..255
  const int nt = tile & 1;
  const int b = mtile >> 5;         // 32 m-tiles per batch row
  const int l0 = (mtile & 31) << 7;
  const int n0 = nt << 8;

  // ---- prologue staging: w_dw transposed -> LDS, segment starts -> LDS
#pragma unroll
  for (int d = 0; d < KW; ++d) wdt[d][t] = w_dw[t * KW + d];
  if (t < BM) {
    int l = l0 + t;
    const int* sb = segb + b * NS * 2;
    int st = 0;
#pragma unroll
    for (int s = 0; s < NS; ++s) {
      int a0 = sb[2 * s], a1 = sb[2 * s + 1];
      if (l >= a0 && l < a1) st = a0;
    }
    segst[t] = st;
  }
  __syncthreads();

  // ---- per-thread staging geometry: 2 rows x 4 channels per K-step
  const int c4 = t & 7;
  const int r0 = (t >> 3) * 2;
  int nv0 = (l0 + r0) - segst[r0];
  if (nv0 > 4) nv0 = 4;
  int nv1 = (l0 + r0 + 1) - segst[r0 + 1];
  if (nv1 > 4) nv1 = 4;
  const int fastpath = __all((nv0 == 4) & (nv1 == 4));

  // x row pointers (clamped low edge; clamped rows are always masked off)
  const float* xrow[6];
#pragma unroll
  for (int m = 0; m < 6; ++m) {
    int lr = l0 + r0 - 4 + m;
    if (lr < 0) lr = 0;
    xrow[m] = x + (size_t)(b * L_ + lr) * C_ + c4 * 4;
  }

  // B staging: 1024 16B-chunks/step; chunk q = i*512+t; n=q>>2, c=q&3
  const int n_0 = t >> 2, c_0 = t & 3;
  const int n_1 = 128 + (t >> 2);
  const bf16* gB0 = wbf + (size_t)(n0 + n_0) * C_ + (c_0 ^ ((n_0 >> 1) & 3)) * 8;
  const bf16* gB1 = wbf + (size_t)(n0 + n_1) * C_ + (c_0 ^ ((n_1 >> 1) & 3)) * 8;
  const int wuni = t & ~63;
  const int dB0 = wuni * 8;          // bf16 elems (HW adds lane*16B)
  const int dB1 = (512 + wuni) * 8;

  f32x4 acc[4][4];
#pragma unroll
  for (int i = 0; i < 4; ++i)
#pragma unroll
    for (int j = 0; j < 4; ++j) acc[i][j] = (f32x4){0.f, 0.f, 0.f, 0.f};

  auto issueB = [&](int kk) {
    const int k0 = kk * BK;
    bf16* base = (bf16*)Bs[kk & 1];
    GLOAD_LDS16(gB0 + k0, base + dB0);
    GLOAD_LDS16(gB1 + k0, base + dB1);
  };

  auto issueX = [&](int kk, float4 (&vx)[6]) {
    const int k0 = kk * BK;
#pragma unroll
    for (int m = 0; m < 6; ++m) vx[m] = *(const float4*)(xrow[m] + k0);
  };

  auto conv = [&](int kk, float4 (&v)[6]) {
    const int p = kk & 1;
    const int k0c = kk * BK + c4 * 4;
    float4 wt[KW];
#pragma unroll
    for (int d = 0; d < KW; ++d) wt[d] = *(const float4*)&wdt[d][k0c];
    if (fastpath) {
#pragma unroll
      for (int j = 0; j < 2; ++j) {
        bf16x4 h;
#pragma unroll
        for (int i = 0; i < 4; ++i) {
          float a = 0.f;
#pragma unroll
          for (int dd = 0; dd < KW; ++dd)  // tap idx dd uses x row l-(4-dd)
            a = fmaf(((const float*)&wt[dd])[i], ((const float*)&v[j + dd])[i], a);
          h[i] = (bf16)a;
        }
        *(bf16x4*)&dws[p][r0 + j][c4 * 4] = h;
      }
    } else {
#pragma unroll
      for (int j = 0; j < 2; ++j) {
        const int nv = j ? nv1 : nv0;
        bf16x4 h;
#pragma unroll
        for (int i = 0; i < 4; ++i) {
          float a = 0.f;
#pragma unroll
          for (int dd = 0; dd < KW; ++dd) {
            float w = (4 - dd <= nv) ? ((const float*)&wt[dd])[i] : 0.f;
            a = fmaf(w, ((const float*)&v[j + dd])[i], a);
          }
          h[i] = (bf16)a;
        }
        *(bf16x4*)&dws[p][r0 + j][c4 * 4] = h;
      }
    }
  };

  auto mma = [&](int kk) {
    const int p = kk & 1;
    bf16x8 afr[4];
#pragma unroll
    for (int mf = 0; mf < 4; ++mf)
      afr[mf] =
          *(const bf16x8*)&dws[p][wm * 64 + mf * 16 + (lane & 15)][(lane >> 4) * 8];
#pragma unroll
    for (int nf = 0; nf < 4; ++nf) {
      const int nl = wn * 64 + nf * 16 + (lane & 15);
      const int ph = (lane >> 4) ^ ((nl >> 1) & 3);
      bf16x8 bfr = *(const bf16x8*)&Bs[p][nl * 32 + ph * 8];
#pragma unroll
      for (int mf = 0; mf < 4; ++mf)
        acc[mf][nf] = __builtin_amdgcn_mfma_f32_16x16x32_bf16(
            afr[mf], bfr, acc[mf][nf], 0, 0, 0);
    }
  };

  float4 vx0[6], vx1[6];

  // ---- pipeline prologue
  issueB(0);
  __builtin_amdgcn_sched_barrier(0);
  issueX(0, vx0);
  issueX(1, vx1);
  __builtin_amdgcn_sched_barrier(0);
  conv(0, vx0);  // auto-wait drains B(0)+x(0); x(1) stays in flight
  PRE_BARRIER6;

  // ---- main loop: iters k=0..13 (x(k+1) consumed, x(k+2)+B(k+1) issued)
#pragma unroll 1
  for (int k2 = 0; k2 < 14; k2 += 2) {
    issueB(k2 + 1);
    __builtin_amdgcn_sched_barrier(0);
    issueX(k2 + 2, vx0);
    __builtin_amdgcn_sched_barrier(0);
    mma(k2);
    conv(k2 + 1, vx1);
    PRE_BARRIER6;

    issueB(k2 + 2);
    __builtin_amdgcn_sched_barrier(0);
    issueX(k2 + 3, vx1);
    __builtin_amdgcn_sched_barrier(0);
    mma(k2 + 1);
    conv(k2 + 2, vx0);
    PRE_BARRIER6;
  }
  // ---- iter k=14: last B issue, no more x
  issueB(15);
  __builtin_amdgcn_sched_barrier(0);
  mma(14);
  conv(15, vx1);
  PRE_BARRIER0;
  // ---- iter k=15
  mma(15);

  // ---- epilogue: fp32 + bias2 (b_pw + W.b_dw, fp32-exact; conv is bias-free)
  const int col0 = n0 + wn * 64 + (lane & 15);
  float bia[4];
#pragma unroll
  for (int nf = 0; nf < 4; ++nf) bia[nf] = bias2[col0 + nf * 16];
  const int rb0 = l0 + wm * 64 + ((lane >> 4) << 2);
#pragma unroll
  for (int mf = 0; mf < 4; ++mf) {
#pragma unroll
    for (int i = 0; i < 4; ++i) {
      const int row = rb0 + mf * 16 + i;
      float* o = out + (size_t)(b * L_ + row) * C_ + col0;
#pragma unroll
      for (int nf = 0; nf < 4; ++nf) o[nf * 16] = acc[mf][nf][i] + bia[nf];
    }
  }
}

extern "C" void kernel_launch(void* const* d_in, const int* in_sizes, int n_in,
                              void* d_out, int out_size, void* d_ws,
                              size_t ws_size, hipStream_t stream) {
  const float* x = (const float*)d_in[0];
  const int* segb = (const int*)d_in[1];      // [B][S][2] int32
  const float* w_dw = (const float*)d_in[2];  // [C][K]
  const float* b_dw = (const float*)d_in[3];  // [C]
  const float* w_pw = (const float*)d_in[4];  // [C_out][C_in]
  const float* b_pw = (const float*)d_in[5];  // [C]
  float* out = (float*)d_out;

  bf16* wbf = (bf16*)d_ws;                             // 512 KB
  float* bias2 = (float*)((char*)d_ws + C_ * C_ * 2);  // 2 KB

  prep_kernel<<<C_, 256, 0, stream>>>(w_pw, b_dw, b_pw, wbf, bias2);
  fused_dwconv_gemm<<<(NB * L_ / BM) * (C_ / BN), 512, 0, stream>>>(
      x, segb, w_dw, wbf, bias2, out);
}

// Round 4
// 46.594 us; speedup vs baseline: 1.5484x; 1.2423x over previous
//
#include <hip/hip_runtime.h>
#include <hip/hip_bf16.h>

typedef __bf16 bf16;
typedef __bf16 bf16x2 __attribute__((ext_vector_type(2)));
typedef __bf16 bf16x4 __attribute__((ext_vector_type(4)));
typedef __bf16 bf16x8 __attribute__((ext_vector_type(8)));
typedef float f32x4 __attribute__((ext_vector_type(4)));

#define NB 8
#define L_ 4096
#define C_ 512
#define KW 5
#define NS 8
#define BM 128
#define BN 512
#define BK 32
#define NT 1024
#define KSTEPS 16

#define GLOAD_LDS16(g, l)                                                      \
  __builtin_amdgcn_global_load_lds(                                            \
      (const __attribute__((address_space(1))) void*)(g),                      \
      (__attribute__((address_space(3))) void*)(l), 16, 0, 0)

// raw barrier with counted vmem wait; lgkmcnt(0) flushes ds_writes
#define PRE_BARRIER(N)                                                         \
  do {                                                                         \
    asm volatile("s_waitcnt vmcnt(" #N ") lgkmcnt(0)" ::: "memory");           \
    __builtin_amdgcn_sched_barrier(0);                                         \
    __builtin_amdgcn_s_barrier();                                              \
    __builtin_amdgcn_sched_barrier(0);                                         \
  } while (0)

// ---------------------------------------------------------------------------
// prep: w_pw fp32 -> bf16; bias2[n] = b_pw[n] + sum_k b_dw[k]*w_pw[n][k]
// ---------------------------------------------------------------------------
__global__ __launch_bounds__(256) void prep_kernel(
    const float* __restrict__ w_pw, const float* __restrict__ b_dw,
    const float* __restrict__ b_pw, bf16* __restrict__ wbf,
    float* __restrict__ bias2) {
  const int n = blockIdx.x;   // 0..511
  const int t = threadIdx.x;  // 0..255
  float2 v = *(const float2*)(w_pw + n * C_ + 2 * t);
  bf16x2 hv;
  hv[0] = (bf16)v.x;
  hv[1] = (bf16)v.y;
  *(bf16x2*)(wbf + n * C_ + 2 * t) = hv;
  float2 bb = *(const float2*)(b_dw + 2 * t);
  float s = v.x * bb.x + v.y * bb.y;
#pragma unroll
  for (int off = 32; off; off >>= 1) s += __shfl_down(s, off, 64);
  __shared__ float part[4];
  if ((t & 63) == 0) part[t >> 6] = s;
  __syncthreads();
  if (t == 0) bias2[n] = b_pw[n] + part[0] + part[1] + part[2] + part[3];
}

// ---------------------------------------------------------------------------
// fused: x staged once/K-step into LDS (fp32), segment-causal conv -> bf16
//        dws LDS, MFMA GEMM vs full N=512. 256 blocks x 1024 thr (16 waves).
// ---------------------------------------------------------------------------
__global__ __launch_bounds__(NT) void fused_dwconv_gemm(
    const float* __restrict__ x, const int* __restrict__ segb,
    const float* __restrict__ w_dw, const bf16* __restrict__ wbf,
    const float* __restrict__ bias2, float* __restrict__ out) {
  __shared__ __align__(16) bf16 Bs[2][BN * BK];       // 64 KB, chunk-XOR swz
  __shared__ __align__(16) bf16 dws[2][BM][40];       // 20 KB (80B rows)
  __shared__ __align__(16) float xs[2][BM + 4][BK];   // 33 KB (128B rows)
  __shared__ __align__(16) float wdt[KW][C_];         // 10 KB
  __shared__ int segst[BM];

  const int t = threadIdx.x;
  const int lane = t & 63;
  const int wid = t >> 6;   // 0..15
  const int wm = wid >> 2;  // 0..3
  const int wn = wid & 3;   // 0..3

  const int b = blockIdx.x >> 5;          // 32 m-tiles per batch row
  const int l0 = (blockIdx.x & 31) << 7;  // tile * 128

  // ---- prologue LDS fills
  if (t < C_) {
#pragma unroll
    for (int d = 0; d < KW; ++d) wdt[d][t] = w_dw[t * KW + d];
  }
  if (t < BM) {
    int l = l0 + t;
    const int* sb = segb + b * NS * 2;
    int st = 0;
#pragma unroll
    for (int s = 0; s < NS; ++s) {
      int a0 = sb[2 * s], a1 = sb[2 * s + 1];
      if (l >= a0 && l < a1) st = a0;
    }
    segst[t] = st;
  }
  __syncthreads();

  // ---- per-thread geometry: 1 row x 4 channels
  const int gr = t >> 3;  // 0..127: row (staging AND conv)
  const int gc = t & 7;   // channel quad within BK
  int nv = (l0 + gr) - segst[gr];
  if (nv > 4) nv = 4;
  const bool fast = __all(nv == 4);

  const float* gxp = x + (size_t)(b * L_ + l0 + gr) * C_ + gc * 4;
  const int h = wid * 2 + lane;  // halo chunk id (valid for lane<2)
  const int hr = h >> 3, hc = h & 7;
  int hl = l0 - 4 + hr;
  if (hl < 0) hl = 0;  // garbage rows are weight-masked by nv
  const float* gxh = x + (size_t)(b * L_ + hl) * C_ + hc * 4;

  // ---- B staging (2048 16B chunks/step): q=i*NT+t, n=q>>2, c=q&3
  const int nB0 = t >> 2, cB0 = t & 3;
  const int nB1 = (NT + t) >> 2, cB1 = t & 3;
  const bf16* gB0 = wbf + (size_t)nB0 * C_ + (cB0 ^ ((nB0 >> 1) & 3)) * 8;
  const bf16* gB1 = wbf + (size_t)nB1 * C_ + (cB1 ^ ((nB1 >> 1) & 3)) * 8;
  const int dB0 = (t & ~63) * 8;
  const int dB1 = (NT + (t & ~63)) * 8;

  f32x4 acc[2][8];
#pragma unroll
  for (int i = 0; i < 2; ++i)
#pragma unroll
    for (int j = 0; j < 8; ++j) acc[i][j] = (f32x4){0.f, 0.f, 0.f, 0.f};

  auto issueB = [&](int kk) {
    bf16* base = (bf16*)Bs[kk & 1];
    GLOAD_LDS16(gB0 + kk * BK, base + dB0);
    GLOAD_LDS16(gB1 + kk * BK, base + dB1);
  };

  auto issueGX = [&](int kk, float4& m4, float4& h4) {
    m4 = *(const float4*)(gxp + kk * BK);
    if (lane < 2) h4 = *(const float4*)(gxh + kk * BK);
  };

  auto stageX = [&](int kk, const float4& m4, const float4& h4) {
    const int p = kk & 1;
    *(float4*)&xs[p][gr + 4][gc * 4] = m4;
    if (lane < 2) *(float4*)&xs[p][hr][hc * 4] = h4;
  };

  auto conv = [&](int kk) {
    const int p = kk & 1;
    const int k0c = kk * BK + gc * 4;
    float w[KW][4];
#pragma unroll
    for (int m = 0; m < KW; ++m) {
      float4 wv = *(const float4*)&wdt[m][k0c];
      w[m][0] = wv.x; w[m][1] = wv.y; w[m][2] = wv.z; w[m][3] = wv.w;
    }
    if (!fast) {
#pragma unroll
      for (int m = 0; m < KW; ++m)
#pragma unroll
        for (int i = 0; i < 4; ++i)
          w[m][i] = (4 - m <= nv) ? w[m][i] : 0.f;
    }
    f32x4 a = (f32x4){0.f, 0.f, 0.f, 0.f};
#pragma unroll
    for (int m = 0; m < KW; ++m) {  // tap m: x row (l0+gr)-(4-m) = xs[gr+m]
      f32x4 xv = *(const f32x4*)&xs[p][gr + m][gc * 4];
#pragma unroll
      for (int i = 0; i < 4; ++i) a[i] = fmaf(w[m][i], xv[i], a[i]);
    }
    bf16x4 hq;
#pragma unroll
    for (int i = 0; i < 4; ++i) hq[i] = (bf16)a[i];
    *(bf16x4*)&dws[p][gr][gc * 4] = hq;
  };

  auto mma = [&](int kk) {
    const int p = kk & 1;
    bf16x8 afr[2];
#pragma unroll
    for (int mf = 0; mf < 2; ++mf)
      afr[mf] = *(const bf16x8*)&dws[p][wm * 32 + mf * 16 + (lane & 15)]
                                     [(lane >> 4) * 8];
#pragma unroll
    for (int nf = 0; nf < 8; ++nf) {
      const int nl = wn * 128 + nf * 16 + (lane & 15);
      const int ph = (lane >> 4) ^ ((nl >> 1) & 3);
      bf16x8 bfr = *(const bf16x8*)&Bs[p][nl * 32 + ph * 8];
#pragma unroll
      for (int mf = 0; mf < 2; ++mf)
        acc[mf][nf] = __builtin_amdgcn_mfma_f32_16x16x32_bf16(
            afr[mf], bfr, acc[mf][nf], 0, 0, 0);
    }
  };

  float4 gm0, gm1, gh0, gh1;

  // ---- pipeline prologue
  issueGX(0, gm0, gh0);
  issueGX(1, gm1, gh1);
  stageX(0, gm0, gh0);  // auto-waits its loads
  issueGX(2, gm0, gh0);
  PRE_BARRIER(4);       // xs(0) visible; gx1,gx2 stay in flight
  stageX(1, gm1, gh1);
  issueB(0);
  issueGX(3, gm1, gh1);
  conv(0);
  PRE_BARRIER(2);       // drains gx2+B0, keeps gx3

  // ---- main loop: steps k=0..11 (x issued 4 ahead, staged 2 ahead)
#pragma unroll 1
  for (int k2 = 0; k2 < 12; k2 += 2) {
    issueB(k2 + 1);
    stageX(k2 + 2, gm0, gh0);
    issueGX(k2 + 4, gm0, gh0);
    conv(k2 + 1);
    mma(k2);
    PRE_BARRIER(2);  // drains gx(k+3)+B(k+1), keeps gx(k+4)

    issueB(k2 + 2);
    stageX(k2 + 3, gm1, gh1);
    issueGX(k2 + 5, gm1, gh1);
    conv(k2 + 2);
    mma(k2 + 1);
    PRE_BARRIER(2);
  }
  // ---- tail: k=12..15
  issueB(13);
  stageX(14, gm0, gh0);
  conv(13);
  mma(12);
  PRE_BARRIER(0);
  issueB(14);
  stageX(15, gm1, gh1);
  conv(14);
  mma(13);
  PRE_BARRIER(0);
  issueB(15);
  conv(15);
  mma(14);
  PRE_BARRIER(0);
  mma(15);

  // ---- epilogue: fp32 + bias2 (b_pw + W.b_dw folded fp32-exact)
  const int col0 = wn * 128 + (lane & 15);
  float bia[8];
#pragma unroll
  for (int nf = 0; nf < 8; ++nf) bia[nf] = bias2[col0 + nf * 16];
  const int rb0 = l0 + wm * 32 + ((lane >> 4) << 2);
#pragma unroll
  for (int mf = 0; mf < 2; ++mf) {
#pragma unroll
    for (int i = 0; i < 4; ++i) {
      const int row = rb0 + mf * 16 + i;
      float* o = out + (size_t)(b * L_ + row) * C_ + col0;
#pragma unroll
      for (int nf = 0; nf < 8; ++nf) o[nf * 16] = acc[mf][nf][i] + bia[nf];
    }
  }
}

extern "C" void kernel_launch(void* const* d_in, const int* in_sizes, int n_in,
                              void* d_out, int out_size, void* d_ws,
                              size_t ws_size, hipStream_t stream) {
  const float* x = (const float*)d_in[0];
  const int* segb = (const int*)d_in[1];      // [B][S][2] int32
  const float* w_dw = (const float*)d_in[2];  // [C][K]
  const float* b_dw = (const float*)d_in[3];  // [C]
  const float* w_pw = (const float*)d_in[4];  // [C_out][C_in]
  const float* b_pw = (const float*)d_in[5];  // [C]
  float* out = (float*)d_out;

  bf16* wbf = (bf16*)d_ws;                             // 512 KB
  float* bias2 = (float*)((char*)d_ws + C_ * C_ * 2);  // 2 KB

  prep_kernel<<<C_, 256, 0, stream>>>(w_pw, b_dw, b_pw, wbf, bias2);
  fused_dwconv_gemm<<<NB * L_ / BM, NT, 0, stream>>>(x, segb, w_dw, wbf,
                                                     bias2, out);
}